// Round 2
// baseline (436.276 us; speedup 1.0000x reference)
//
#include <hip/hip_runtime.h>
#include <math.h>

#define BLOCK 256
#define IMG_H 512
#define IMG_W 512
#define PLANES 96                    // 32 batch * 3 channels
#define RS 64                        // output rows per strip
#define NSTRIP (IMG_H / RS)          // 8
#define NBLOCKS (PLANES * NSTRIP)    // 768
#define NPHASE (RS + 10)             // 74 input rows streamed per strip
#define N_TOTAL 25165824.0f

struct GW { float w[11]; };

__global__ __launch_bounds__(BLOCK, 2)
void ssim_stream(const float* __restrict__ pred,
                 const float* __restrict__ targ,
                 float* __restrict__ accum, GW gw) {
    const int c      = threadIdx.x;          // owns output cols 2c, 2c+1
    const int strip  = blockIdx.x & (NSTRIP - 1);
    const int plane  = blockIdx.x / NSTRIP;
    const int r0     = strip * RS;
    const float* P   = pred + (size_t)plane * (IMG_H * IMG_W);
    const float* T   = targ + (size_t)plane * (IMG_H * IMG_W);
    const int colbase = 2 * c - 8;           // input window [colbase, colbase+16)
    const bool interior = (c >= 4) && (c <= 252);

    const float C1v = 0.0001f;
    const float C2v = 0.0009f;

    // rolling history of horizontal-conv rows: 5 quantities x 11 rows x 2 cols
    float h[5][11][2];
    float lsum = 0.f;

    for (int base = 0; base < 77; base += 11) {
#pragma unroll
        for (int ph = 0; ph < 11; ++ph) {
            const int m = base + ph;                 // uniform
            if (m < NPHASE) {
                const int r = r0 - 5 + m;            // uniform per block
                float hv[5][2];

                if (r >= 0 && r < IMG_H) {
                    const float* rp = P + ((size_t)r << 9);
                    const float* tp = T + ((size_t)r << 9);
                    float x[16], y[16];
                    if (interior) {
#pragma unroll
                        for (int v = 0; v < 8; ++v) {
                            float2 a = *(const float2*)(rp + colbase + 2 * v);
                            float2 b = *(const float2*)(tp + colbase + 2 * v);
                            x[2*v] = a.x; x[2*v+1] = a.y;
                            y[2*v] = b.x; y[2*v+1] = b.y;
                        }
                    } else {
#pragma unroll
                        for (int i = 0; i < 16; ++i) {
                            const int col = colbase + i;
                            const bool ok = (col >= 0) && (col < IMG_W);
                            x[i] = ok ? rp[col] : 0.f;
                            y[i] = ok ? tp[col] : 0.f;
                        }
                    }
                    // products for the 12 cols used by both output windows
                    float pp[12], tt[12], pt[12];
#pragma unroll
                    for (int i = 0; i < 12; ++i) {
                        const float a = x[i + 3], b = y[i + 3];
                        pp[i] = a * a; tt[i] = b * b; pt[i] = a * b;
                    }
#pragma unroll
                    for (int j = 0; j < 2; ++j) {
                        float s0 = 0.f, s1 = 0.f, s2 = 0.f, s3 = 0.f, s4 = 0.f;
#pragma unroll
                        for (int k = 0; k < 11; ++k) {
                            const float w = gw.w[k];
                            s0 = fmaf(w, x[3 + j + k], s0);
                            s1 = fmaf(w, y[3 + j + k], s1);
                            s2 = fmaf(w, pp[j + k], s2);
                            s3 = fmaf(w, tt[j + k], s3);
                            s4 = fmaf(w, pt[j + k], s4);
                        }
                        hv[0][j] = s0; hv[1][j] = s1; hv[2][j] = s2;
                        hv[3][j] = s3; hv[4][j] = s4;
                    }
                } else {
#pragma unroll
                    for (int q = 0; q < 5; ++q) { hv[q][0] = 0.f; hv[q][1] = 0.f; }
                }

#pragma unroll
                for (int q = 0; q < 5; ++q) {
                    h[q][ph][0] = hv[q][0];
                    h[q][ph][1] = hv[q][1];
                }

                if (m >= 10) {                       // uniform; output row r-5
#pragma unroll
                    for (int j = 0; j < 2; ++j) {
                        float o0 = 0.f, o1 = 0.f, o2 = 0.f, o3 = 0.f, o4 = 0.f;
#pragma unroll
                        for (int k = 0; k < 11; ++k) {
                            const int s = (ph + 1 + k) % 11;   // compile-time
                            const float w = gw.w[k];
                            o0 = fmaf(w, h[0][s][j], o0);
                            o1 = fmaf(w, h[1][s][j], o1);
                            o2 = fmaf(w, h[2][s][j], o2);
                            o3 = fmaf(w, h[3][s][j], o3);
                            o4 = fmaf(w, h[4][s][j], o4);
                        }
                        const float mu1  = o0, mu2 = o1;
                        const float mu1s = mu1 * mu1;
                        const float mu2s = mu2 * mu2;
                        const float mu12 = mu1 * mu2;
                        const float sg1  = o2 - mu1s;
                        const float sg2  = o3 - mu2s;
                        const float sg12 = o4 - mu12;
                        const float num  = fmaf(2.f, mu12, C1v) * fmaf(2.f, sg12, C2v);
                        const float den  = (mu1s + mu2s + C1v) * (sg1 + sg2 + C2v);
                        lsum = fmaf(num, __builtin_amdgcn_rcpf(den), lsum);
                    }
                }
            }
        }
    }

    // wave reduce + one atomic per wave (no LDS)
#pragma unroll
    for (int off = 32; off > 0; off >>= 1) lsum += __shfl_down(lsum, off, 64);
    if ((threadIdx.x & 63) == 0) atomicAdd(accum, lsum);
}

__global__ void ssim_finalize(const float* __restrict__ accum, float* __restrict__ out) {
    out[0] = 1.0f - accum[0] * (1.0f / N_TOTAL);
}

extern "C" void kernel_launch(void* const* d_in, const int* in_sizes, int n_in,
                              void* d_out, int out_size, void* d_ws, size_t ws_size,
                              hipStream_t stream) {
    const float* pred = (const float*)d_in[0];
    const float* targ = (const float*)d_in[1];
    float* out = (float*)d_out;
    float* ws  = (float*)d_ws;

    // Gaussian weights on host -> kernel args -> SGPRs (no per-thread expf)
    GW gw;
    {
        double g[11], s = 0.0;
        for (int k = 0; k < 11; ++k) {
            const double d = (double)(k - 5);
            g[k] = exp(-d * d / 4.5);
            s += g[k];
        }
        for (int k = 0; k < 11; ++k) gw.w[k] = (float)(g[k] / s);
    }

    hipMemsetAsync(ws, 0, sizeof(float), stream);
    ssim_stream<<<NBLOCKS, BLOCK, 0, stream>>>(pred, targ, ws, gw);
    ssim_finalize<<<1, 1, 0, stream>>>(ws, out);
}

// Round 3
// 310.661 us; speedup vs baseline: 1.4043x; 1.4043x over previous
//
#include <hip/hip_runtime.h>
#include <math.h>

#define BLOCK 256
#define TW 64
#define TH 16
#define HR (TH + 10)            // 26 horizontal-result rows per tile
#define PAD 4
#define SW (TW + PAD)           // 68-float LDS row stride (16B aligned, breaks pow2 banks)
#define IMG 512
#define PLANES 96               // 32 batch * 3 channels
#define NBLOCKS (PLANES * (IMG / TW) * (IMG / TH))   // 96*8*32 = 24576
#define N_TOTAL 25165824.0f
#define NACC 128

struct GW { float w[11]; };

__global__ __launch_bounds__(BLOCK, 4)
void ssim_main(const float* __restrict__ pred,
               const float* __restrict__ targ,
               float* __restrict__ accum, GW gw) {
    __shared__ float s_h[5][HR][SW];     // 35360 B -> 4 blocks/CU
    __shared__ float s_red[BLOCK / 64];

    const int bx    = blockIdx.x;
    const int plane = bx >> 8;           // 256 tiles per plane
    const int rem   = bx & 255;
    const int ty    = rem >> 3;          // 0..31 row strips
    const int tx    = rem & 7;           // 0..7 col tiles
    const int r0    = ty * TH;
    const int c0    = tx * TW;

    const float* P = pred + (size_t)plane * (IMG * IMG);
    const float* T = targ + (size_t)plane * (IMG * IMG);

    // ---------------- Phase 1: horizontal conv (one slot per thread) ----------------
    const int s = threadIdx.x;
    if (s < HR * 8) {
        const int hr  = s >> 3;          // 0..25 -> LDS row
        const int seg = s & 7;           // 8-col segment
        const int gr  = r0 - 5 + hr;     // global input row
        const int a   = c0 + seg * 8 - 8;  // aligned 24-col load window

        float x[24], y[24];
        const bool interior = (ty > 0) & (ty < 31) & (tx > 0) & (tx < 7);

        if (interior) {                  // block-uniform: no bounds checks at all
            const float* rp = P + ((size_t)gr << 9) + a;
            const float* tp = T + ((size_t)gr << 9) + a;
#pragma unroll
            for (int v = 0; v < 6; ++v) {
                float4 fp = *(const float4*)(rp + 4 * v);
                float4 ft = *(const float4*)(tp + 4 * v);
                x[4*v+0]=fp.x; x[4*v+1]=fp.y; x[4*v+2]=fp.z; x[4*v+3]=fp.w;
                y[4*v+0]=ft.x; y[4*v+1]=ft.y; y[4*v+2]=ft.z; y[4*v+3]=ft.w;
            }
        } else if (gr >= 0 && gr < IMG) {
            const float* rp = P + ((size_t)gr << 9);
            const float* tp = T + ((size_t)gr << 9);
#pragma unroll
            for (int v = 0; v < 6; ++v) {
                const int col = a + 4 * v;
                if (col >= 0 && col + 3 < IMG) {
                    float4 fp = *(const float4*)(rp + col);
                    float4 ft = *(const float4*)(tp + col);
                    x[4*v+0]=fp.x; x[4*v+1]=fp.y; x[4*v+2]=fp.z; x[4*v+3]=fp.w;
                    y[4*v+0]=ft.x; y[4*v+1]=ft.y; y[4*v+2]=ft.z; y[4*v+3]=ft.w;
                } else {
                    x[4*v+0]=0.f; x[4*v+1]=0.f; x[4*v+2]=0.f; x[4*v+3]=0.f;
                    y[4*v+0]=0.f; y[4*v+1]=0.f; y[4*v+2]=0.f; y[4*v+3]=0.f;
                }
            }
        } else {
#pragma unroll
            for (int i = 0; i < 24; ++i) { x[i] = 0.f; y[i] = 0.f; }
        }

        // second-moment products for cols 3..20 (18 values)
        float pp[18], tt[18], pt[18];
#pragma unroll
        for (int i = 0; i < 18; ++i) {
            const float xa = x[i + 3], yb = y[i + 3];
            pp[i] = xa * xa; tt[i] = yb * yb; pt[i] = xa * yb;
        }

        float hp[8], ht[8], hpp[8], htt[8], hpt[8];
#pragma unroll
        for (int j = 0; j < 8; ++j) {
            float a0 = 0.f, a1 = 0.f, a2 = 0.f, a3 = 0.f, a4 = 0.f;
#pragma unroll
            for (int k = 0; k < 11; ++k) {
                const float w = gw.w[k];
                a0 = fmaf(w, x[3 + j + k], a0);
                a1 = fmaf(w, y[3 + j + k], a1);
                a2 = fmaf(w, pp[j + k], a2);
                a3 = fmaf(w, tt[j + k], a3);
                a4 = fmaf(w, pt[j + k], a4);
            }
            hp[j]=a0; ht[j]=a1; hpp[j]=a2; htt[j]=a3; hpt[j]=a4;
        }

        const int cseg = seg * 8;        // 16B-aligned within the 68-float row
        float4* d0 = (float4*)&s_h[0][hr][cseg];
        float4* d1 = (float4*)&s_h[1][hr][cseg];
        float4* d2 = (float4*)&s_h[2][hr][cseg];
        float4* d3 = (float4*)&s_h[3][hr][cseg];
        float4* d4 = (float4*)&s_h[4][hr][cseg];
        d0[0] = make_float4(hp[0],hp[1],hp[2],hp[3]);     d0[1] = make_float4(hp[4],hp[5],hp[6],hp[7]);
        d1[0] = make_float4(ht[0],ht[1],ht[2],ht[3]);     d1[1] = make_float4(ht[4],ht[5],ht[6],ht[7]);
        d2[0] = make_float4(hpp[0],hpp[1],hpp[2],hpp[3]); d2[1] = make_float4(hpp[4],hpp[5],hpp[6],hpp[7]);
        d3[0] = make_float4(htt[0],htt[1],htt[2],htt[3]); d3[1] = make_float4(htt[4],htt[5],htt[6],htt[7]);
        d4[0] = make_float4(hpt[0],hpt[1],hpt[2],hpt[3]); d4[1] = make_float4(hpt[4],hpt[5],hpt[6],hpt[7]);
    }

    __syncthreads();

    // ---------------- Phase 2: vertical conv + SSIM ----------------
    const int c     = threadIdx.x & 63;
    const int rbase = (threadIdx.x >> 6) * 4;    // 4 output rows per thread

    float acc[5][4];
#pragma unroll
    for (int q = 0; q < 5; ++q) {
        float v[15];
#pragma unroll
        for (int i = 0; i < 15; ++i) v[i] = s_h[q][rbase + i][c];  // stride-1 lanes: conflict-free
#pragma unroll
        for (int i = 0; i < 4; ++i) {
            float a = 0.f;
#pragma unroll
            for (int k = 0; k < 11; ++k) a = fmaf(gw.w[k], v[i + k], a);
            acc[q][i] = a;
        }
    }

    const float C1v = 0.0001f;
    const float C2v = 0.0009f;
    float lsum = 0.f;
#pragma unroll
    for (int i = 0; i < 4; ++i) {
        const float mu1  = acc[0][i];
        const float mu2  = acc[1][i];
        const float mu1s = mu1 * mu1;
        const float mu2s = mu2 * mu2;
        const float mu12 = mu1 * mu2;
        const float sg1  = acc[2][i] - mu1s;
        const float sg2  = acc[3][i] - mu2s;
        const float sg12 = acc[4][i] - mu12;
        const float num  = fmaf(2.f, mu12, C1v) * fmaf(2.f, sg12, C2v);
        const float den  = (mu1s + mu2s + C1v) * (sg1 + sg2 + C2v);
        lsum = fmaf(num, __builtin_amdgcn_rcpf(den), lsum);
    }

    // ---------------- Reduction: wave shfl -> LDS -> 1 atomic/block ----------------
#pragma unroll
    for (int off = 32; off > 0; off >>= 1) lsum += __shfl_down(lsum, off, 64);
    const int wave = threadIdx.x >> 6;
    if ((threadIdx.x & 63) == 0) s_red[wave] = lsum;
    __syncthreads();
    if (threadIdx.x == 0) {
        atomicAdd(&accum[bx & (NACC - 1)],
                  s_red[0] + s_red[1] + s_red[2] + s_red[3]);
    }
}

__global__ void ssim_finalize(const float* __restrict__ accum, float* __restrict__ out) {
    const int l = threadIdx.x;                       // 64 threads
    float v = accum[l] + accum[l + 64];
#pragma unroll
    for (int off = 32; off > 0; off >>= 1) v += __shfl_down(v, off, 64);
    if (l == 0) out[0] = 1.0f - v * (1.0f / N_TOTAL);
}

extern "C" void kernel_launch(void* const* d_in, const int* in_sizes, int n_in,
                              void* d_out, int out_size, void* d_ws, size_t ws_size,
                              hipStream_t stream) {
    const float* pred = (const float*)d_in[0];
    const float* targ = (const float*)d_in[1];
    float* out = (float*)d_out;
    float* ws  = (float*)d_ws;

    GW gw;
    {
        double g[11], sum = 0.0;
        for (int k = 0; k < 11; ++k) {
            const double d = (double)(k - 5);
            g[k] = exp(-d * d / 4.5);
            sum += g[k];
        }
        for (int k = 0; k < 11; ++k) gw.w[k] = (float)(g[k] / sum);
    }

    hipMemsetAsync(ws, 0, NACC * sizeof(float), stream);
    ssim_main<<<NBLOCKS, BLOCK, 0, stream>>>(pred, targ, ws, gw);
    ssim_finalize<<<1, 64, 0, stream>>>(ws, out);
}

// Round 4
// 300.613 us; speedup vs baseline: 1.4513x; 1.0334x over previous
//
#include <hip/hip_runtime.h>
#include <hip/hip_bf16.h>
#include <math.h>

#define BLOCK 256
#define TW 64
#define TH 16
#define HR (TH + 10)            // 26 horizontal-result rows per tile
#define SW2 72                  // bf16 elems per LDS row (144 B stride, mult of 16)
#define PLANE (HR * SW2)        // 1872 bf16 elems (3744 B, mult of 16)
#define IMG 512
#define PLANES 96               // 32 batch * 3 channels
#define NBLOCKS (PLANES * (IMG / TW) * (IMG / TH))   // 24576
#define N_TOTAL 25165824.0f
#define NACC 128

struct GW { float w[11]; };

__device__ __forceinline__ unsigned int pk2(float a, float b) {
    union { __hip_bfloat162 h; unsigned int u; } cv;
    cv.h = __float22bfloat162_rn(make_float2(a, b));
    return cv.u;
}

__global__ __launch_bounds__(BLOCK, 6)
void ssim_main(const float* __restrict__ pred,
               const float* __restrict__ targ,
               float* __restrict__ accum, GW gw) {
    __shared__ unsigned short s_h[5 * PLANE];   // 18720 B -> 6+ blocks/CU
    __shared__ float s_red[BLOCK / 64];

    const int bx    = blockIdx.x;
    const int plane = bx >> 8;
    const int rem   = bx & 255;
    const int ty    = rem >> 3;          // 0..31 row strips
    const int tx    = rem & 7;           // 0..7 col tiles
    const int r0    = ty * TH;
    const int c0    = tx * TW;

    const float* P = pred + (size_t)plane * (IMG * IMG);
    const float* T = targ + (size_t)plane * (IMG * IMG);

    // ---------------- Phase 1: horizontal conv -> bf16 LDS ----------------
    const int s = threadIdx.x;
    if (s < HR * 8) {
        const int hr  = s >> 3;
        const int seg = s & 7;
        const int gr  = r0 - 5 + hr;
        const int a   = c0 + seg * 8 - 8;

        float x[24], y[24];
        const bool interior = (ty > 0) & (ty < 31) & (tx > 0) & (tx < 7);

        if (interior) {
            const float* rp = P + ((size_t)gr << 9) + a;
            const float* tp = T + ((size_t)gr << 9) + a;
#pragma unroll
            for (int v = 0; v < 6; ++v) {
                float4 fp = *(const float4*)(rp + 4 * v);
                float4 ft = *(const float4*)(tp + 4 * v);
                x[4*v+0]=fp.x; x[4*v+1]=fp.y; x[4*v+2]=fp.z; x[4*v+3]=fp.w;
                y[4*v+0]=ft.x; y[4*v+1]=ft.y; y[4*v+2]=ft.z; y[4*v+3]=ft.w;
            }
        } else if (gr >= 0 && gr < IMG) {
            const float* rp = P + ((size_t)gr << 9);
            const float* tp = T + ((size_t)gr << 9);
#pragma unroll
            for (int v = 0; v < 6; ++v) {
                const int col = a + 4 * v;
                if (col >= 0 && col + 3 < IMG) {
                    float4 fp = *(const float4*)(rp + col);
                    float4 ft = *(const float4*)(tp + col);
                    x[4*v+0]=fp.x; x[4*v+1]=fp.y; x[4*v+2]=fp.z; x[4*v+3]=fp.w;
                    y[4*v+0]=ft.x; y[4*v+1]=ft.y; y[4*v+2]=ft.z; y[4*v+3]=ft.w;
                } else {
                    x[4*v+0]=0.f; x[4*v+1]=0.f; x[4*v+2]=0.f; x[4*v+3]=0.f;
                    y[4*v+0]=0.f; y[4*v+1]=0.f; y[4*v+2]=0.f; y[4*v+3]=0.f;
                }
            }
        } else {
#pragma unroll
            for (int i = 0; i < 24; ++i) { x[i] = 0.f; y[i] = 0.f; }
        }

        float pp[18], tt[18], pt[18];
#pragma unroll
        for (int i = 0; i < 18; ++i) {
            const float xa = x[i + 3], yb = y[i + 3];
            pp[i] = xa * xa; tt[i] = yb * yb; pt[i] = xa * yb;
        }

        float hp[8], ht[8], hpp[8], htt[8], hpt[8];
#pragma unroll
        for (int j = 0; j < 8; ++j) {
            float a0 = 0.f, a1 = 0.f, a2 = 0.f, a3 = 0.f, a4 = 0.f;
#pragma unroll
            for (int k = 0; k < 11; ++k) {
                const float w = gw.w[k];
                a0 = fmaf(w, x[3 + j + k], a0);
                a1 = fmaf(w, y[3 + j + k], a1);
                a2 = fmaf(w, pp[j + k], a2);
                a3 = fmaf(w, tt[j + k], a3);
                a4 = fmaf(w, pt[j + k], a4);
            }
            hp[j]=a0; ht[j]=a1; hpp[j]=a2; htt[j]=a3; hpt[j]=a4;
        }

        // pack to bf16, one 16-B store per quantity (16-B aligned: 144*hr + 16*seg)
        const int eo = hr * SW2 + seg * 8;
        {
            uint4 u;
            u.x = pk2(hp[0],hp[1]); u.y = pk2(hp[2],hp[3]); u.z = pk2(hp[4],hp[5]); u.w = pk2(hp[6],hp[7]);
            *(uint4*)&s_h[0*PLANE + eo] = u;
            u.x = pk2(ht[0],ht[1]); u.y = pk2(ht[2],ht[3]); u.z = pk2(ht[4],ht[5]); u.w = pk2(ht[6],ht[7]);
            *(uint4*)&s_h[1*PLANE + eo] = u;
            u.x = pk2(hpp[0],hpp[1]); u.y = pk2(hpp[2],hpp[3]); u.z = pk2(hpp[4],hpp[5]); u.w = pk2(hpp[6],hpp[7]);
            *(uint4*)&s_h[2*PLANE + eo] = u;
            u.x = pk2(htt[0],htt[1]); u.y = pk2(htt[2],htt[3]); u.z = pk2(htt[4],htt[5]); u.w = pk2(htt[6],htt[7]);
            *(uint4*)&s_h[3*PLANE + eo] = u;
            u.x = pk2(hpt[0],hpt[1]); u.y = pk2(hpt[2],hpt[3]); u.z = pk2(hpt[4],hpt[5]); u.w = pk2(hpt[6],hpt[7]);
            *(uint4*)&s_h[4*PLANE + eo] = u;
        }
    }

    __syncthreads();

    // ---------------- Phase 2: vertical conv + SSIM (2 cols x 2 rows / thread) ----
    const int cp = threadIdx.x & 31;     // col pair: cols 2cp, 2cp+1
    const int rg = threadIdx.x >> 5;     // 0..7 -> out rows 2rg, 2rg+1

    float acc[5][4];                     // [q][r0c0, r0c1, r1c0, r1c1]
#pragma unroll
    for (int q = 0; q < 5; ++q) {
        const unsigned short* pl = &s_h[q * PLANE];
        unsigned int d[12];
#pragma unroll
        for (int i = 0; i < 12; ++i)
            d[i] = *(const unsigned int*)&pl[(2 * rg + i) * SW2 + cp * 2];
        float lo[12], hi[12];
#pragma unroll
        for (int i = 0; i < 12; ++i) {
            lo[i] = __uint_as_float(d[i] << 16);
            hi[i] = __uint_as_float(d[i] & 0xffff0000u);
        }
        float e0 = 0.f, o0 = 0.f, e1 = 0.f, o1 = 0.f;
#pragma unroll
        for (int k = 0; k < 11; ++k) {
            const float w = gw.w[k];
            e0 = fmaf(w, lo[k],     e0);
            o0 = fmaf(w, hi[k],     o0);
            e1 = fmaf(w, lo[k + 1], e1);
            o1 = fmaf(w, hi[k + 1], o1);
        }
        acc[q][0] = e0; acc[q][1] = o0; acc[q][2] = e1; acc[q][3] = o1;
    }

    const float C1v = 0.0001f;
    const float C2v = 0.0009f;
    float lsum = 0.f;
#pragma unroll
    for (int i = 0; i < 4; ++i) {
        const float mu1  = acc[0][i];
        const float mu2  = acc[1][i];
        const float mu1s = mu1 * mu1;
        const float mu2s = mu2 * mu2;
        const float mu12 = mu1 * mu2;
        const float sg1  = acc[2][i] - mu1s;
        const float sg2  = acc[3][i] - mu2s;
        const float sg12 = acc[4][i] - mu12;
        const float num  = fmaf(2.f, mu12, C1v) * fmaf(2.f, sg12, C2v);
        const float den  = (mu1s + mu2s + C1v) * (sg1 + sg2 + C2v);
        lsum = fmaf(num, __builtin_amdgcn_rcpf(den), lsum);
    }

    // ---------------- Reduction ----------------
#pragma unroll
    for (int off = 32; off > 0; off >>= 1) lsum += __shfl_down(lsum, off, 64);
    const int wave = threadIdx.x >> 6;
    if ((threadIdx.x & 63) == 0) s_red[wave] = lsum;
    __syncthreads();
    if (threadIdx.x == 0) {
        atomicAdd(&accum[bx & (NACC - 1)],
                  s_red[0] + s_red[1] + s_red[2] + s_red[3]);
    }
}

__global__ void ssim_finalize(const float* __restrict__ accum, float* __restrict__ out) {
    const int l = threadIdx.x;
    float v = accum[l] + accum[l + 64];
#pragma unroll
    for (int off = 32; off > 0; off >>= 1) v += __shfl_down(v, off, 64);
    if (l == 0) out[0] = 1.0f - v * (1.0f / N_TOTAL);
}

extern "C" void kernel_launch(void* const* d_in, const int* in_sizes, int n_in,
                              void* d_out, int out_size, void* d_ws, size_t ws_size,
                              hipStream_t stream) {
    const float* pred = (const float*)d_in[0];
    const float* targ = (const float*)d_in[1];
    float* out = (float*)d_out;
    float* ws  = (float*)d_ws;

    GW gw;
    {
        double g[11], sum = 0.0;
        for (int k = 0; k < 11; ++k) {
            const double d = (double)(k - 5);
            g[k] = exp(-d * d / 4.5);
            sum += g[k];
        }
        for (int k = 0; k < 11; ++k) gw.w[k] = (float)(g[k] / sum);
    }

    hipMemsetAsync(ws, 0, NACC * sizeof(float), stream);
    ssim_main<<<NBLOCKS, BLOCK, 0, stream>>>(pred, targ, ws, gw);
    ssim_finalize<<<1, 64, 0, stream>>>(ws, out);
}

// Round 5
// 296.722 us; speedup vs baseline: 1.4703x; 1.0131x over previous
//
#include <hip/hip_runtime.h>
#include <hip/hip_bf16.h>
#include <math.h>

#define BLOCK 256
#define TW 64
#define TH 16
#define IMG 512
#define NBLOCKS (96 * (IMG / TW) * (IMG / TH))   // 24576
#define N_TOTAL 25165824.0f
#define NACC 128
#define HSTR 40                                   // bf16 stride of one H^T column (80 B)

typedef float f32x4 __attribute__((ext_vector_type(4)));
typedef short s16x8 __attribute__((ext_vector_type(8)));

struct WB { unsigned short b[11]; float corr; };

union FR { unsigned int u[4]; s16x8 s; };

__device__ __forceinline__ unsigned int pk2(float a, float b) {
    union { __hip_bfloat162 h; unsigned int u; } cv;
    cv.h = __float22bfloat162_rn(make_float2(a, b));
    return cv.u;
}

__global__ __launch_bounds__(BLOCK, 4)
void ssim_mfma(const float* __restrict__ pred,
               const float* __restrict__ targ,
               float* __restrict__ accum, WB wb) {
    __shared__ unsigned short s_w[2][16][32];      // [0]=B_h: w[k-n-3]; [1]=A_v: w[k-m]
    __shared__ unsigned short s_ht[5][64][HSTR];   // H^T planes, bf16: [quantity][col][row]
    __shared__ float s_red[4];

    const int tid = threadIdx.x;

    // ---- build weight matrices in LDS (once per block) ----
    for (int e = tid; e < 1024; e += BLOCK) {
        const int mat = e >> 9;
        const int m   = (e >> 5) & 15;
        const int k   = e & 31;
        const int idx = k - m - (mat == 0 ? 3 : 0);
        s_w[mat][m][k] = (idx >= 0 && idx <= 10) ? wb.b[idx] : (unsigned short)0;
    }

    const int bx    = blockIdx.x;
    const int plane = bx >> 8;
    const int rem   = bx & 255;
    const int ty    = rem >> 3;          // 0..31
    const int tx    = rem & 7;           // 0..7
    const int r0    = ty * TH;
    const int c0    = tx * TW;

    const float* P = pred + (size_t)plane * (IMG * IMG);
    const float* T = targ + (size_t)plane * (IMG * IMG);

    const int wave = tid >> 6;
    const int lane = tid & 63;
    const int l15  = lane & 15;
    const int quad = lane >> 4;

    __syncthreads();

    // ================= Phase H: horizontal conv via MFMA =================
    // Wave handles col-group g=wave (out cols c0+16g..+16). K-window = input
    // cols [c0+16g-8, +24). A = data (m=l15 -> H row, k=quad*8+j -> col),
    // B = Toeplitz weights w[k-n-3]. D[m=quad*4+reg -> H row][n=l15 -> col].
    FR bw; bw.s = *(const s16x8*)&s_w[0][l15][quad * 8];
    const int g  = wave;
    const int cb = c0 + 16 * g - 8 + 8 * quad;

    const f32x4 z = {0.f, 0.f, 0.f, 0.f};

    for (int mt = 0; mt < 2; ++mt) {
        const int hrow0 = 16 * mt;
        const int gr    = r0 - 5 + hrow0 + l15;    // global input row for A-row l15

        float x8[8], y8[8];
        if (gr >= 0 && gr < IMG) {
            const float* rp = P + ((size_t)gr << 9);
            const float* tp = T + ((size_t)gr << 9);
            if (cb >= 0 && cb + 8 <= IMG) {
                float4 a0 = *(const float4*)(rp + cb);
                float4 a1 = *(const float4*)(rp + cb + 4);
                float4 b0 = *(const float4*)(tp + cb);
                float4 b1 = *(const float4*)(tp + cb + 4);
                x8[0]=a0.x; x8[1]=a0.y; x8[2]=a0.z; x8[3]=a0.w;
                x8[4]=a1.x; x8[5]=a1.y; x8[6]=a1.z; x8[7]=a1.w;
                y8[0]=b0.x; y8[1]=b0.y; y8[2]=b0.z; y8[3]=b0.w;
                y8[4]=b1.x; y8[5]=b1.y; y8[6]=b1.z; y8[7]=b1.w;
            } else {
#pragma unroll
                for (int i = 0; i < 8; ++i) {
                    const int cc = cb + i;
                    const int cs = min(max(cc, 0), IMG - 1);
                    const float vx = rp[cs], vy = tp[cs];
                    const bool ok = (cc >= 0) && (cc < IMG);
                    x8[i] = ok ? vx : 0.f;
                    y8[i] = ok ? vy : 0.f;
                }
            }
        } else {
#pragma unroll
            for (int i = 0; i < 8; ++i) { x8[i] = 0.f; y8[i] = 0.f; }
        }

        FR ax, ay, axx, ayy, axy;
#pragma unroll
        for (int p = 0; p < 4; ++p) {
            const float xa = x8[2*p], xb = x8[2*p+1];
            const float ya = y8[2*p], yb = y8[2*p+1];
            ax.u[p]  = pk2(xa, xb);
            ay.u[p]  = pk2(ya, yb);
            axx.u[p] = pk2(xa * xa, xb * xb);
            ayy.u[p] = pk2(ya * ya, yb * yb);
            axy.u[p] = pk2(xa * ya, xb * yb);
        }

        f32x4 d0 = __builtin_amdgcn_mfma_f32_16x16x32_bf16(ax.s,  bw.s, z, 0, 0, 0);
        f32x4 d1 = __builtin_amdgcn_mfma_f32_16x16x32_bf16(ay.s,  bw.s, z, 0, 0, 0);
        f32x4 d2 = __builtin_amdgcn_mfma_f32_16x16x32_bf16(axx.s, bw.s, z, 0, 0, 0);
        f32x4 d3 = __builtin_amdgcn_mfma_f32_16x16x32_bf16(ayy.s, bw.s, z, 0, 0, 0);
        f32x4 d4 = __builtin_amdgcn_mfma_f32_16x16x32_bf16(axy.s, bw.s, z, 0, 0, 0);

        // D: 4 consecutive H rows (hrow0+4*quad+reg) of col 16g+l15 -> one b64 store
        const int hcol = 16 * g + l15;
        const int hr   = hrow0 + 4 * quad;
        *(uint2*)&s_ht[0][hcol][hr] = make_uint2(pk2(d0[0], d0[1]), pk2(d0[2], d0[3]));
        *(uint2*)&s_ht[1][hcol][hr] = make_uint2(pk2(d1[0], d1[1]), pk2(d1[2], d1[3]));
        *(uint2*)&s_ht[2][hcol][hr] = make_uint2(pk2(d2[0], d2[1]), pk2(d2[2], d2[3]));
        *(uint2*)&s_ht[3][hcol][hr] = make_uint2(pk2(d3[0], d3[1]), pk2(d3[2], d3[3]));
        *(uint2*)&s_ht[4][hcol][hr] = make_uint2(pk2(d4[0], d4[1]), pk2(d4[2], d4[3]));
    }

    __syncthreads();

    // ================= Phase V: vertical conv via MFMA + SSIM =================
    // Wave handles col-group cg=wave. A = weights w[k-m], B = H^T (lane l15 = col,
    // k = H rows quad*8+j -> one b128). D[m=quad*4+reg -> out row][n=l15 -> col].
    FR aw; aw.s = *(const s16x8*)&s_w[1][l15][quad * 8];
    const int col = 16 * wave + l15;

    f32x4 acc[5];
#pragma unroll
    for (int q = 0; q < 5; ++q) {
        FR b; b.s = *(const s16x8*)&s_ht[q][col][quad * 8];
        acc[q] = __builtin_amdgcn_mfma_f32_16x16x32_bf16(aw.s, b.s, z, 0, 0, 0);
    }

    const float corr = wb.corr;
    const float C1v = 0.0001f;
    const float C2v = 0.0009f;
    float lsum = 0.f;
#pragma unroll
    for (int i = 0; i < 4; ++i) {
        const float mu1 = acc[0][i] * corr;
        const float mu2 = acc[1][i] * corr;
        const float exx = acc[2][i] * corr;
        const float eyy = acc[3][i] * corr;
        const float exy = acc[4][i] * corr;
        const float mu1s = mu1 * mu1;
        const float mu2s = mu2 * mu2;
        const float mu12 = mu1 * mu2;
        const float sg1  = exx - mu1s;
        const float sg2  = eyy - mu2s;
        const float sg12 = exy - mu12;
        const float num  = fmaf(2.f, mu12, C1v) * fmaf(2.f, sg12, C2v);
        const float den  = (mu1s + mu2s + C1v) * (sg1 + sg2 + C2v);
        lsum = fmaf(num, __builtin_amdgcn_rcpf(den), lsum);
    }

    // ---- reduction: wave shfl -> LDS -> one atomic per block ----
#pragma unroll
    for (int off = 32; off > 0; off >>= 1) lsum += __shfl_down(lsum, off, 64);
    if (lane == 0) s_red[wave] = lsum;
    __syncthreads();
    if (tid == 0) {
        atomicAdd(&accum[bx & (NACC - 1)],
                  s_red[0] + s_red[1] + s_red[2] + s_red[3]);
    }
}

__global__ void ssim_finalize(const float* __restrict__ accum, float* __restrict__ out) {
    const int l = threadIdx.x;
    float v = accum[l] + accum[l + 64];
#pragma unroll
    for (int off = 32; off > 0; off >>= 1) v += __shfl_down(v, off, 64);
    if (l == 0) out[0] = 1.0f - v * (1.0f / N_TOTAL);
}

extern "C" void kernel_launch(void* const* d_in, const int* in_sizes, int n_in,
                              void* d_out, int out_size, void* d_ws, size_t ws_size,
                              hipStream_t stream) {
    const float* pred = (const float*)d_in[0];
    const float* targ = (const float*)d_in[1];
    float* out = (float*)d_out;
    float* ws  = (float*)d_ws;

    WB wb;
    {
        double gg[11], sum = 0.0;
        for (int k = 0; k < 11; ++k) {
            const double d = (double)(k - 5);
            gg[k] = exp(-d * d / 4.5);
            sum += gg[k];
        }
        double sbf = 0.0;
        for (int k = 0; k < 11; ++k) {
            union { float f; unsigned int u; } cv;
            cv.f = (float)(gg[k] / sum);
            // round-to-nearest-even fp32 -> bf16
            const unsigned int r = (cv.u + 0x7fffu + ((cv.u >> 16) & 1u)) >> 16;
            wb.b[k] = (unsigned short)r;
            union { float f; unsigned int u; } bk;
            bk.u = r << 16;
            sbf += (double)bk.f;
        }
        wb.corr = (float)(1.0 / (sbf * sbf));   // undo (sum w̃)^2 from the two passes
    }

    hipMemsetAsync(ws, 0, NACC * sizeof(float), stream);
    ssim_mfma<<<NBLOCKS, BLOCK, 0, stream>>>(pred, targ, ws, wb);
    ssim_finalize<<<1, 64, 0, stream>>>(ws, out);
}

// Round 6
// 273.486 us; speedup vs baseline: 1.5952x; 1.0850x over previous
//
#include <hip/hip_runtime.h>
#include <hip/hip_bf16.h>
#include <math.h>

#define BLOCK 256
#define IMG 512
#define CHUNK 128               // output rows per wave-strip
#define NSTEP 9                 // H steps (8 V steps) per strip
#define RSTR 40                 // ring stride in bf16 els per col (80 B, 16B-mult)
#define NBLOCKS 3072            // 12288 wave-strips / 4 waves per block
#define NACC 128
#define N_TOTAL 25165824.0f

typedef float f32x4 __attribute__((ext_vector_type(4)));
typedef short s16x8 __attribute__((ext_vector_type(8)));

struct WB { unsigned short b[11]; float corr; };
union FR { unsigned int u[4]; s16x8 s; };

__device__ __forceinline__ unsigned int pk2(float a, float b) {
    union { __hip_bfloat162 h; unsigned int u; } cv;
    cv.h = __float22bfloat162_rn(make_float2(a, b));
    return cv.u;
}

__global__ __launch_bounds__(BLOCK, 5)
void ssim_stream(const float* __restrict__ pred,
                 const float* __restrict__ targ,
                 float* __restrict__ accum, WB wb) {
    // [0] = B_h: w[k-n-3]; [1] = A_v off0: w[(k-m)&31]; [2] = A_v off16: w[(k-m-16)&31]
    __shared__ unsigned short s_w[3][16][32];                 // 3 KB
    __shared__ unsigned short s_ring[4][5][16][RSTR];         // 25.6 KB, wave-private slices

    const int tid = threadIdx.x;
    for (int e = tid; e < 3 * 512; e += BLOCK) {
        const int mat = e >> 9;
        const int m   = (e >> 5) & 15;
        const int k   = e & 31;
        int idx;
        if (mat == 0) idx = k - m - 3;
        else          idx = (k - m - (mat == 2 ? 16 : 0)) & 31;
        s_w[mat][m][k] = (idx >= 0 && idx <= 10) ? wb.b[idx] : (unsigned short)0;
    }
    __syncthreads();            // the ONLY barrier

    const int wave = tid >> 6;
    const int lane = tid & 63;
    const int l15  = lane & 15;
    const int quad = lane >> 4;

    const int S     = blockIdx.x * 4 + wave;   // wave-strip id
    const int plane = S >> 7;                  // 128 strips per plane
    const int rem   = S & 127;
    const int C0    = (rem >> 2) * 16;         // 32 col strips
    const int R0    = (rem & 3) * CHUNK;       // 4 row chunks

    const float* P = pred + (size_t)plane * (IMG * IMG);
    const float* T = targ + (size_t)plane * (IMG * IMG);

    FR bw;  bw.s  = *(const s16x8*)&s_w[0][l15][quad * 8];
    FR aw0; aw0.s = *(const s16x8*)&s_w[1][l15][quad * 8];
    FR aw1; aw1.s = *(const s16x8*)&s_w[2][l15][quad * 8];

    unsigned short (*ring)[16][RSTR] = s_ring[wave];

    const int  cb    = C0 - 8 + 8 * quad;                // 8-col aligned input run
    const bool colok = (cb >= 0) && (cb <= IMG - 8);     // all-or-nothing at edges
    const float corr = wb.corr;
    const float C1v = 0.0001f, C2v = 0.0009f;
    const f32x4 z = {0.f, 0.f, 0.f, 0.f};
    float lsum = 0.f;

    // ---- prologue: load step 0 (input rows R0-5+l15) ----
    float xc[8], yc[8];
    {
        const int gr = R0 - 5 + l15;
        const bool ok = colok && (gr >= 0) && (gr < IMG);
        if (ok) {
            const float* rp = P + ((size_t)gr << 9) + cb;
            const float* tp = T + ((size_t)gr << 9) + cb;
            float4 a0 = *(const float4*)rp, a1 = *(const float4*)(rp + 4);
            float4 b0 = *(const float4*)tp, b1 = *(const float4*)(tp + 4);
            xc[0]=a0.x; xc[1]=a0.y; xc[2]=a0.z; xc[3]=a0.w;
            xc[4]=a1.x; xc[5]=a1.y; xc[6]=a1.z; xc[7]=a1.w;
            yc[0]=b0.x; yc[1]=b0.y; yc[2]=b0.z; yc[3]=b0.w;
            yc[4]=b1.x; yc[5]=b1.y; yc[6]=b1.z; yc[7]=b1.w;
        } else {
#pragma unroll
            for (int i = 0; i < 8; ++i) { xc[i] = 0.f; yc[i] = 0.f; }
        }
    }

    for (int s = 0; s < NSTEP; ++s) {
        // ---- prefetch step s+1 (issued before any use of xc/yc results) ----
        float xn[8], yn[8];
        const bool have_next = (s + 1 < NSTEP);
        if (have_next) {
            const int gr = R0 - 5 + 16 * (s + 1) + l15;
            const bool ok = colok && (gr >= 0) && (gr < IMG);
            if (ok) {
                const float* rp = P + ((size_t)gr << 9) + cb;
                const float* tp = T + ((size_t)gr << 9) + cb;
                float4 a0 = *(const float4*)rp, a1 = *(const float4*)(rp + 4);
                float4 b0 = *(const float4*)tp, b1 = *(const float4*)(tp + 4);
                xn[0]=a0.x; xn[1]=a0.y; xn[2]=a0.z; xn[3]=a0.w;
                xn[4]=a1.x; xn[5]=a1.y; xn[6]=a1.z; xn[7]=a1.w;
                yn[0]=b0.x; yn[1]=b0.y; yn[2]=b0.z; yn[3]=b0.w;
                yn[4]=b1.x; yn[5]=b1.y; yn[6]=b1.z; yn[7]=b1.w;
            } else {
#pragma unroll
                for (int i = 0; i < 8; ++i) { xn[i] = 0.f; yn[i] = 0.f; }
            }
        } else {
#pragma unroll
            for (int i = 0; i < 8; ++i) { xn[i] = 0.f; yn[i] = 0.f; }
        }

        // ---- H: pack + 5 MFMA -> ring positions (16s + m) & 31 ----
        FR ax, ay, axx, ayy, axy;
#pragma unroll
        for (int p = 0; p < 4; ++p) {
            const float xa = xc[2*p], xb = xc[2*p+1];
            const float ya = yc[2*p], yb = yc[2*p+1];
            ax.u[p]  = pk2(xa, xb);
            ay.u[p]  = pk2(ya, yb);
            axx.u[p] = pk2(xa * xa, xb * xb);
            ayy.u[p] = pk2(ya * ya, yb * yb);
            axy.u[p] = pk2(xa * ya, xb * yb);
        }
        f32x4 d0 = __builtin_amdgcn_mfma_f32_16x16x32_bf16(ax.s,  bw.s, z, 0, 0, 0);
        f32x4 d1 = __builtin_amdgcn_mfma_f32_16x16x32_bf16(ay.s,  bw.s, z, 0, 0, 0);
        f32x4 d2 = __builtin_amdgcn_mfma_f32_16x16x32_bf16(axx.s, bw.s, z, 0, 0, 0);
        f32x4 d3 = __builtin_amdgcn_mfma_f32_16x16x32_bf16(ayy.s, bw.s, z, 0, 0, 0);
        f32x4 d4 = __builtin_amdgcn_mfma_f32_16x16x32_bf16(axy.s, bw.s, z, 0, 0, 0);

        const int pb = (16 * s + 4 * quad) & 31;   // 4-aligned, never wraps in-run
        *(uint2*)&ring[0][l15][pb] = make_uint2(pk2(d0[0], d0[1]), pk2(d0[2], d0[3]));
        *(uint2*)&ring[1][l15][pb] = make_uint2(pk2(d1[0], d1[1]), pk2(d1[2], d1[3]));
        *(uint2*)&ring[2][l15][pb] = make_uint2(pk2(d2[0], d2[1]), pk2(d2[2], d2[3]));
        *(uint2*)&ring[3][l15][pb] = make_uint2(pk2(d3[0], d3[1]), pk2(d3[2], d3[3]));
        *(uint2*)&ring[4][l15][pb] = make_uint2(pk2(d4[0], d4[1]), pk2(d4[2], d4[3]));

        // ---- V: out rows [R0+16t, +16), intra-wave ds ordering (no barrier) ----
        if (s >= 1) {
            const int t = s - 1;
            const FR aw = (t & 1) ? aw1 : aw0;     // ring offset 16t mod 32
            f32x4 acc[5];
#pragma unroll
            for (int q = 0; q < 5; ++q) {
                FR b; b.s = *(const s16x8*)&ring[q][l15][quad * 8];
                acc[q] = __builtin_amdgcn_mfma_f32_16x16x32_bf16(aw.s, b.s, z, 0, 0, 0);
            }
#pragma unroll
            for (int i = 0; i < 4; ++i) {
                const float mu1 = acc[0][i] * corr;
                const float mu2 = acc[1][i] * corr;
                const float exx = acc[2][i] * corr;
                const float eyy = acc[3][i] * corr;
                const float exy = acc[4][i] * corr;
                const float mu1s = mu1 * mu1;
                const float mu2s = mu2 * mu2;
                const float mu12 = mu1 * mu2;
                const float sg1  = exx - mu1s;
                const float sg2  = eyy - mu2s;
                const float sg12 = exy - mu12;
                const float num  = fmaf(2.f, mu12, C1v) * fmaf(2.f, sg12, C2v);
                const float den  = (mu1s + mu2s + C1v) * (sg1 + sg2 + C2v);
                lsum = fmaf(num, __builtin_amdgcn_rcpf(den), lsum);
            }
        }

#pragma unroll
        for (int i = 0; i < 8; ++i) { xc[i] = xn[i]; yc[i] = yn[i]; }
    }

    // ---- wave reduce -> one atomic per wave ----
#pragma unroll
    for (int off = 32; off > 0; off >>= 1) lsum += __shfl_down(lsum, off, 64);
    if (lane == 0) atomicAdd(&accum[S & (NACC - 1)], lsum);
}

__global__ void ssim_finalize(const float* __restrict__ accum, float* __restrict__ out) {
    const int l = threadIdx.x;
    float v = accum[l] + accum[l + 64];
#pragma unroll
    for (int off = 32; off > 0; off >>= 1) v += __shfl_down(v, off, 64);
    if (l == 0) out[0] = 1.0f - v * (1.0f / N_TOTAL);
}

extern "C" void kernel_launch(void* const* d_in, const int* in_sizes, int n_in,
                              void* d_out, int out_size, void* d_ws, size_t ws_size,
                              hipStream_t stream) {
    const float* pred = (const float*)d_in[0];
    const float* targ = (const float*)d_in[1];
    float* out = (float*)d_out;
    float* ws  = (float*)d_ws;

    WB wb;
    {
        double gg[11], sum = 0.0;
        for (int k = 0; k < 11; ++k) {
            const double d = (double)(k - 5);
            gg[k] = exp(-d * d / 4.5);
            sum += gg[k];
        }
        double sbf = 0.0;
        for (int k = 0; k < 11; ++k) {
            union { float f; unsigned int u; } cv;
            cv.f = (float)(gg[k] / sum);
            const unsigned int r = (cv.u + 0x7fffu + ((cv.u >> 16) & 1u)) >> 16;
            wb.b[k] = (unsigned short)r;
            union { float f; unsigned int u; } bk;
            bk.u = r << 16;
            sbf += (double)bk.f;
        }
        wb.corr = (float)(1.0 / (sbf * sbf));
    }

    hipMemsetAsync(ws, 0, NACC * sizeof(float), stream);
    ssim_stream<<<NBLOCKS, BLOCK, 0, stream>>>(pred, targ, ws, wb);
    ssim_finalize<<<1, 64, 0, stream>>>(ws, out);
}

// Round 7
// 265.407 us; speedup vs baseline: 1.6438x; 1.0304x over previous
//
#include <hip/hip_runtime.h>
#include <hip/hip_bf16.h>
#include <math.h>

#define BLOCK 256
#define IMG 512
#define SW 84                   // staged bf16 stride (168 B: non-pow2 banks, 8B-mult)
#define RSTR 40                 // ring bf16 stride per col (80 B, 16B-mult)
#define NBLOCKS 3072            // 96 planes * 8 col-tiles * 4 row-chunks
#define NACC 128
#define N_TOTAL 25165824.0f

typedef float f32x4 __attribute__((ext_vector_type(4)));
typedef short s16x8 __attribute__((ext_vector_type(8)));

struct WB { unsigned short b[11]; float corr; };
union FR { unsigned int u[4]; s16x8 s; };

__device__ __forceinline__ unsigned int pk2(float a, float b) {
    union { __hip_bfloat162 h; unsigned int u; } cv;
    cv.h = __float22bfloat162_rn(make_float2(a, b));
    return cv.u;
}

__device__ __forceinline__ void stage5(unsigned short (*sq)[16][SW],
                                       int r, int i, float4 xv, float4 yv) {
    *(uint2*)&sq[0][r][4*i] = make_uint2(pk2(xv.x,xv.y), pk2(xv.z,xv.w));
    *(uint2*)&sq[1][r][4*i] = make_uint2(pk2(yv.x,yv.y), pk2(yv.z,yv.w));
    *(uint2*)&sq[2][r][4*i] = make_uint2(pk2(xv.x*xv.x,xv.y*xv.y), pk2(xv.z*xv.z,xv.w*xv.w));
    *(uint2*)&sq[3][r][4*i] = make_uint2(pk2(yv.x*yv.x,yv.y*yv.y), pk2(yv.z*yv.z,yv.w*yv.w));
    *(uint2*)&sq[4][r][4*i] = make_uint2(pk2(xv.x*yv.x,xv.y*yv.y), pk2(xv.z*yv.z,xv.w*yv.w));
}

__global__ __launch_bounds__(BLOCK, 3)
void ssim_tiled(const float* __restrict__ pred,
                const float* __restrict__ targ,
                float* __restrict__ accum, WB wb) {
    __shared__ unsigned short s_w[3][16][32];
    __shared__ unsigned short s_q[5][16][SW];
    __shared__ unsigned short s_ring[5][64][RSTR];

    const int tid = threadIdx.x;
    for (int e = tid; e < 3 * 512; e += BLOCK) {
        const int mat = e >> 9;
        const int m   = (e >> 5) & 15;
        const int k   = e & 31;
        int idx;
        if (mat == 0) idx = k - m - 3;
        else          idx = (k - m - (mat == 2 ? 16 : 0)) & 31;
        s_w[mat][m][k] = (idx >= 0 && idx <= 10) ? wb.b[idx] : (unsigned short)0;
    }

    const int bx    = blockIdx.x;
    const int plane = bx >> 5;
    const int rem   = bx & 31;
    const int tx    = rem >> 2;
    const int ry    = rem & 3;
    const int C0    = tx * 64;
    const int R0    = ry * 128;

    const float* P = pred + (size_t)plane * (IMG * IMG);
    const float* T = targ + (size_t)plane * (IMG * IMG);

    const int w    = tid >> 6;
    const int lane = tid & 63;
    const int l15  = lane & 15;
    const int quad = lane >> 4;

    const int slotA = w * 80 + lane;
    const int rA = slotA / 20, iA = slotA % 20;
    const int colA = C0 - 8 + 4 * iA;
    const bool okcA = (colA >= 0) && (colA + 4 <= IMG);
    const bool hasB = (lane < 16);
    const int slotB = w * 80 + 64 + l15;
    const int rB = slotB / 20, iB = slotB % 20;
    const int colB = C0 - 8 + 4 * iB;
    const bool okcB = (colB >= 0) && (colB + 4 <= IMG);

    const float corr = wb.corr;
    const float C1v = 0.0001f, C2v = 0.0009f;
    const f32x4 z = {0.f, 0.f, 0.f, 0.f};
    float lsum = 0.f;

    float4 xA, yA, xB, yB;
    {
        const int gr = R0 - 5 + rA;
        if (okcA && gr >= 0) {
            xA = *(const float4*)(P + ((size_t)gr << 9) + colA);
            yA = *(const float4*)(T + ((size_t)gr << 9) + colA);
        } else { xA = make_float4(0,0,0,0); yA = make_float4(0,0,0,0); }
        const int grB = R0 - 5 + rB;
        if (hasB && okcB && grB >= 0) {
            xB = *(const float4*)(P + ((size_t)grB << 9) + colB);
            yB = *(const float4*)(T + ((size_t)grB << 9) + colB);
        } else { xB = make_float4(0,0,0,0); yB = make_float4(0,0,0,0); }
    }
    __syncthreads();

    FR bw;  bw.s  = *(const s16x8*)&s_w[0][l15][quad * 8];
    FR aw0; aw0.s = *(const s16x8*)&s_w[1][l15][quad * 8];
    FR aw1; aw1.s = *(const s16x8*)&s_w[2][l15][quad * 8];

    stage5(s_q, rA, iA, xA, yA);
    if (hasB) stage5(s_q, rB, iB, xB, yB);
    __syncthreads();

    const int rcol = 16 * w + l15;

    for (int s = 0; s < 9; ++s) {
        float4 nxA, nyA, nxB, nyB;
        if (s < 8) {
            const int gr = R0 - 5 + 16 * (s + 1) + rA;
            if (okcA && gr < IMG) {
                nxA = *(const float4*)(P + ((size_t)gr << 9) + colA);
                nyA = *(const float4*)(T + ((size_t)gr << 9) + colA);
            } else { nxA = make_float4(0,0,0,0); nyA = make_float4(0,0,0,0); }
            const int grB = R0 - 5 + 16 * (s + 1) + rB;
            if (hasB && okcB && grB < IMG) {
                nxB = *(const float4*)(P + ((size_t)grB << 9) + colB);
                nyB = *(const float4*)(T + ((size_t)grB << 9) + colB);
            } else { nxB = make_float4(0,0,0,0); nyB = make_float4(0,0,0,0); }
        }

        {
            FR a0, a1, a2, a3, a4;
            a0.s = *(const s16x8*)&s_q[0][l15][16*w + 8*quad];
            a1.s = *(const s16x8*)&s_q[1][l15][16*w + 8*quad];
            a2.s = *(const s16x8*)&s_q[2][l15][16*w + 8*quad];
            a3.s = *(const s16x8*)&s_q[3][l15][16*w + 8*quad];
            a4.s = *(const s16x8*)&s_q[4][l15][16*w + 8*quad];
            f32x4 d0 = __builtin_amdgcn_mfma_f32_16x16x32_bf16(a0.s, bw.s, z, 0, 0, 0);
            f32x4 d1 = __builtin_amdgcn_mfma_f32_16x16x32_bf16(a1.s, bw.s, z, 0, 0, 0);
            f32x4 d2 = __builtin_amdgcn_mfma_f32_16x16x32_bf16(a2.s, bw.s, z, 0, 0, 0);
            f32x4 d3 = __builtin_amdgcn_mfma_f32_16x16x32_bf16(a3.s, bw.s, z, 0, 0, 0);
            f32x4 d4 = __builtin_amdgcn_mfma_f32_16x16x32_bf16(a4.s, bw.s, z, 0, 0, 0);
            const int pb = (16 * s + 4 * quad) & 31;
            *(uint2*)&s_ring[0][rcol][pb] = make_uint2(pk2(d0[0],d0[1]), pk2(d0[2],d0[3]));
            *(uint2*)&s_ring[1][rcol][pb] = make_uint2(pk2(d1[0],d1[1]), pk2(d1[2],d1[3]));
            *(uint2*)&s_ring[2][rcol][pb] = make_uint2(pk2(d2[0],d2[1]), pk2(d2[2],d2[3]));
            *(uint2*)&s_ring[3][rcol][pb] = make_uint2(pk2(d3[0],d3[1]), pk2(d3[2],d3[3]));
            *(uint2*)&s_ring[4][rcol][pb] = make_uint2(pk2(d4[0],d4[1]), pk2(d4[2],d4[3]));
        }

        if (s >= 1) {
            const int t = s - 1;
            const FR aw = (t & 1) ? aw1 : aw0;
            f32x4 acc[5];
#pragma unroll
            for (int q = 0; q < 5; ++q) {
                FR b; b.s = *(const s16x8*)&s_ring[q][rcol][quad * 8];
                acc[q] = __builtin_amdgcn_mfma_f32_16x16x32_bf16(aw.s, b.s, z, 0, 0, 0);
            }
#pragma unroll
            for (int i = 0; i < 4; ++i) {
                const float mu1 = acc[0][i] * corr;
                const float mu2 = acc[1][i] * corr;
                const float exx = acc[2][i] * corr;
                const float eyy = acc[3][i] * corr;
                const float exy = acc[4][i] * corr;
                const float mu1s = mu1 * mu1;
                const float mu2s = mu2 * mu2;
                const float mu12 = mu1 * mu2;
                const float sg1  = exx - mu1s;
                const float sg2  = eyy - mu2s;
                const float sg12 = exy - mu12;
                const float num  = fmaf(2.f, mu12, C1v) * fmaf(2.f, sg12, C2v);
                const float den  = (mu1s + mu2s + C1v) * (sg1 + sg2 + C2v);
                lsum = fmaf(num, __builtin_amdgcn_rcpf(den), lsum);
            }
        }

        __syncthreads();

        if (s < 8) {
            stage5(s_q, rA, iA, nxA, nyA);
            if (hasB) stage5(s_q, rB, iB, nxB, nyB);
            __syncthreads();
        }
    }

#pragma unroll
    for (int off = 32; off > 0; off >>= 1) lsum += __shfl_down(lsum, off, 64);
    if (lane == 0) atomicAdd(&accum[(bx * 4 + w) & (NACC - 1)], lsum);
}

__global__ void ssim_finalize(const float* __restrict__ accum, float* __restrict__ out) {
    const int l = threadIdx.x;
    float v = accum[l] + accum[l + 64];
#pragma unroll
    for (int off = 32; off > 0; off >>= 1) v += __shfl_down(v, off, 64);
    if (l == 0) out[0] = 1.0f - v * (1.0f / N_TOTAL);
}

extern "C" void kernel_launch(void* const* d_in, const int* in_sizes, int n_in,
                              void* d_out, int out_size, void* d_ws, size_t ws_size,
                              hipStream_t stream) {
    const float* pred = (const float*)d_in[0];
    const float* targ = (const float*)d_in[1];
    float* out = (float*)d_out;
    float* ws  = (float*)d_ws;

    WB wb;
    {
        double gg[11], sum = 0.0;
        for (int k = 0; k < 11; ++k) {
            const double d = (double)(k - 5);
            gg[k] = exp(-d * d / 4.5);
            sum += gg[k];
        }
        double sbf = 0.0;
        for (int k = 0; k < 11; ++k) {
            union { float f; unsigned int u; } cv;
            cv.f = (float)(gg[k] / sum);
            const unsigned int r = (cv.u + 0x7fffu + ((cv.u >> 16) & 1u)) >> 16;
            wb.b[k] = (unsigned short)r;
            union { float f; unsigned int u; } bk;
            bk.u = r << 16;
            sbf += (double)bk.f;
        }
        wb.corr = (float)(1.0 / (sbf * sbf));
    }

    hipMemsetAsync(ws, 0, NACC * sizeof(float), stream);
    ssim_tiled<<<NBLOCKS, BLOCK, 0, stream>>>(pred, targ, ws, wb);
    ssim_finalize<<<1, 64, 0, stream>>>(ws, out);
}

// Round 8
// 257.576 us; speedup vs baseline: 1.6938x; 1.0304x over previous
//
#include <hip/hip_runtime.h>
#include <hip/hip_bf16.h>
#include <math.h>

#define BLOCK 256
#define IMG 512
#define SW 88                   // staged bf16 stride (176 B: 16B-aligned b128 frags, 2-way banks)
#define RSTR 40                 // ring bf16 stride per col (80 B, 16B-aligned)
#define NBLOCKS 3072            // 96 planes * 8 col-tiles * 4 row-chunks
#define NACC 128
#define N_TOTAL 25165824.0f

typedef float f32x4 __attribute__((ext_vector_type(4)));
typedef short s16x8 __attribute__((ext_vector_type(8)));

struct WB { unsigned short b[11]; float c2; float k1; float k2; };
union FR { unsigned int u[4]; s16x8 s; };

__device__ __forceinline__ unsigned int pk2(float a, float b) {
    union { __hip_bfloat162 h; unsigned int u; } cv;
    cv.h = __float22bfloat162_rn(make_float2(a, b));
    return cv.u;
}

__device__ __forceinline__ void stage5(unsigned short (*sq)[16][SW],
                                       int r, int i, float4 xv, float4 yv) {
    *(uint2*)&sq[0][r][4*i] = make_uint2(pk2(xv.x,xv.y), pk2(xv.z,xv.w));
    *(uint2*)&sq[1][r][4*i] = make_uint2(pk2(yv.x,yv.y), pk2(yv.z,yv.w));
    *(uint2*)&sq[2][r][4*i] = make_uint2(pk2(xv.x*xv.x,xv.y*xv.y), pk2(xv.z*xv.z,xv.w*xv.w));
    *(uint2*)&sq[3][r][4*i] = make_uint2(pk2(yv.x*yv.x,yv.y*yv.y), pk2(yv.z*yv.z,yv.w*yv.w));
    *(uint2*)&sq[4][r][4*i] = make_uint2(pk2(xv.x*yv.x,xv.y*yv.y), pk2(xv.z*yv.z,xv.w*yv.w));
}

__device__ __forceinline__ void load_set(const float* __restrict__ P,
                                         const float* __restrict__ T,
                                         int R0, int step,
                                         int rA, int colA, bool okcA,
                                         bool hasB, int rB, int colB, bool okcB,
                                         float4& xA, float4& yA, float4& xB, float4& yB) {
    const int gr = R0 - 5 + 16 * step + rA;
    if (okcA && gr >= 0 && gr < IMG) {
        xA = *(const float4*)(P + ((size_t)gr << 9) + colA);
        yA = *(const float4*)(T + ((size_t)gr << 9) + colA);
    } else { xA = make_float4(0,0,0,0); yA = make_float4(0,0,0,0); }
    const int grB = R0 - 5 + 16 * step + rB;
    if (hasB && okcB && grB >= 0 && grB < IMG) {
        xB = *(const float4*)(P + ((size_t)grB << 9) + colB);
        yB = *(const float4*)(T + ((size_t)grB << 9) + colB);
    } else { xB = make_float4(0,0,0,0); yB = make_float4(0,0,0,0); }
}

__global__ __launch_bounds__(BLOCK, 3)
void ssim_tiled(const float* __restrict__ pred,
                const float* __restrict__ targ,
                float* __restrict__ accum, WB wb) {
    __shared__ unsigned short s_w[3][16][32];      // 3 KB
    __shared__ unsigned short s_q[5][16][SW];      // 14.1 KB
    __shared__ unsigned short s_ring[5][64][RSTR]; // 25.6 KB

    const int tid = threadIdx.x;
    for (int e = tid; e < 3 * 512; e += BLOCK) {
        const int mat = e >> 9;
        const int m   = (e >> 5) & 15;
        const int k   = e & 31;
        int idx;
        if (mat == 0) idx = k - m - 3;
        else          idx = (k - m - (mat == 2 ? 16 : 0)) & 31;
        s_w[mat][m][k] = (idx >= 0 && idx <= 10) ? wb.b[idx] : (unsigned short)0;
    }

    const int bx    = blockIdx.x;
    const int plane = bx >> 5;
    const int rem   = bx & 31;
    const int tx    = rem >> 2;
    const int ry    = rem & 3;
    const int C0    = tx * 64;
    const int R0    = ry * 128;

    const float* P = pred + (size_t)plane * (IMG * IMG);
    const float* T = targ + (size_t)plane * (IMG * IMG);

    const int w    = tid >> 6;
    const int lane = tid & 63;
    const int l15  = lane & 15;
    const int quad = lane >> 4;

    const int slotA = w * 80 + lane;
    const int rA = slotA / 20, iA = slotA % 20;
    const int colA = C0 - 8 + 4 * iA;
    const bool okcA = (colA >= 0) && (colA + 4 <= IMG);
    const bool hasB = (lane < 16);
    const int slotB = w * 80 + 64 + l15;
    const int rB = slotB / 20, iB = slotB % 20;
    const int colB = C0 - 8 + 4 * iB;
    const bool okcB = (colB >= 0) && (colB + 4 <= IMG);

    const float c2 = wb.c2, K1 = wb.k1, K2 = wb.k2;
    const f32x4 z = {0.f, 0.f, 0.f, 0.f};
    float lsum = 0.f;

    // ---- prologue: step-0 set (staged now) + step-1 set (held) ----
    float4 pxA, pyA, pxB, pyB;
    load_set(P, T, R0, 0, rA, colA, okcA, hasB, rB, colB, okcB, pxA, pyA, pxB, pyB);
    float4 sxA[2], syA[2], sxB[2], syB[2];
    load_set(P, T, R0, 1, rA, colA, okcA, hasB, rB, colB, okcB,
             sxA[1], syA[1], sxB[1], syB[1]);
    __syncthreads();               // s_w ready

    FR bw;  bw.s  = *(const s16x8*)&s_w[0][l15][quad * 8];
    FR aw0; aw0.s = *(const s16x8*)&s_w[1][l15][quad * 8];
    FR aw1; aw1.s = *(const s16x8*)&s_w[2][l15][quad * 8];

    stage5(s_q, rA, iA, pxA, pyA);
    if (hasB) stage5(s_q, rB, iB, pxB, pyB);
    __syncthreads();               // s_q(step0) ready

    const int rcol = 16 * w + l15;

#pragma unroll
    for (int s = 0; s < 9; ++s) {
        // ---- issue loads for step s+2 (consumed at iteration s+1) ----
        if (s < 7) {
            load_set(P, T, R0, s + 2, rA, colA, okcA, hasB, rB, colB, okcB,
                     sxA[s & 1], syA[s & 1], sxB[s & 1], syB[s & 1]);
        }

        // ---- H: 5 b128 A-reads + 5 MFMA -> wave-private ring ----
        {
            FR a0, a1, a2, a3, a4;
            a0.s = *(const s16x8*)&s_q[0][l15][16*w + 8*quad];
            a1.s = *(const s16x8*)&s_q[1][l15][16*w + 8*quad];
            a2.s = *(const s16x8*)&s_q[2][l15][16*w + 8*quad];
            a3.s = *(const s16x8*)&s_q[3][l15][16*w + 8*quad];
            a4.s = *(const s16x8*)&s_q[4][l15][16*w + 8*quad];
            f32x4 d0 = __builtin_amdgcn_mfma_f32_16x16x32_bf16(a0.s, bw.s, z, 0, 0, 0);
            f32x4 d1 = __builtin_amdgcn_mfma_f32_16x16x32_bf16(a1.s, bw.s, z, 0, 0, 0);
            f32x4 d2 = __builtin_amdgcn_mfma_f32_16x16x32_bf16(a2.s, bw.s, z, 0, 0, 0);
            f32x4 d3 = __builtin_amdgcn_mfma_f32_16x16x32_bf16(a3.s, bw.s, z, 0, 0, 0);
            f32x4 d4 = __builtin_amdgcn_mfma_f32_16x16x32_bf16(a4.s, bw.s, z, 0, 0, 0);
            const int pb = (16 * s + 4 * quad) & 31;
            *(uint2*)&s_ring[0][rcol][pb] = make_uint2(pk2(d0[0],d0[1]), pk2(d0[2],d0[3]));
            *(uint2*)&s_ring[1][rcol][pb] = make_uint2(pk2(d1[0],d1[1]), pk2(d1[2],d1[3]));
            *(uint2*)&s_ring[2][rcol][pb] = make_uint2(pk2(d2[0],d2[1]), pk2(d2[2],d2[3]));
            *(uint2*)&s_ring[3][rcol][pb] = make_uint2(pk2(d3[0],d3[1]), pk2(d3[2],d3[3]));
            *(uint2*)&s_ring[4][rcol][pb] = make_uint2(pk2(d4[0],d4[1]), pk2(d4[2],d4[3]));
        }

        // ---- V: out rows [R0+16t, +16) for t=s-1 ----
        if (s >= 1) {
            const FR aw = ((s - 1) & 1) ? aw1 : aw0;
            f32x4 acc[5];
#pragma unroll
            for (int q = 0; q < 5; ++q) {
                FR b; b.s = *(const s16x8*)&s_ring[q][rcol][quad * 8];
                acc[q] = __builtin_amdgcn_mfma_f32_16x16x32_bf16(aw.s, b.s, z, 0, 0, 0);
            }
#pragma unroll
            for (int i = 0; i < 4; ++i) {
                const float u1  = acc[0][i];
                const float u2  = acc[1][i];
                const float m11 = u1 * u1;
                const float m22 = u2 * u2;
                const float m12 = u1 * u2;
                const float e11 = acc[2][i] * c2;
                const float e22 = acc[3][i] * c2;
                const float e12 = acc[4][i] * c2;
                const float A = fmaf(2.f, m12, K1);
                const float B = fmaf(2.f, e12 - m12, K2);
                const float C = m11 + m22 + K1;
                const float D = (e11 + e22) - (m11 + m22) + K2;
                lsum = fmaf(A * B, __builtin_amdgcn_rcpf(C * D), lsum);
            }
        }

        __syncthreads();           // all consumers done with s_q(step s)

        // ---- stage set for step s+1 (loaded at iteration s-1: ~1.7 iters of cover) ----
        if (s < 8) {
            stage5(s_q, rA, iA, sxA[(s + 1) & 1], syA[(s + 1) & 1]);
            if (hasB) stage5(s_q, rB, iB, sxB[(s + 1) & 1], syB[(s + 1) & 1]);
            __syncthreads();
        }
    }

#pragma unroll
    for (int off = 32; off > 0; off >>= 1) lsum += __shfl_down(lsum, off, 64);
    if (lane == 0) atomicAdd(&accum[(bx * 4 + w) & (NACC - 1)], lsum);
}

__global__ void ssim_finalize(const float* __restrict__ accum, float* __restrict__ out) {
    const int l = threadIdx.x;
    float v = accum[l] + accum[l + 64];
#pragma unroll
    for (int off = 32; off > 0; off >>= 1) v += __shfl_down(v, off, 64);
    if (l == 0) out[0] = 1.0f - v * (1.0f / N_TOTAL);
}

extern "C" void kernel_launch(void* const* d_in, const int* in_sizes, int n_in,
                              void* d_out, int out_size, void* d_ws, size_t ws_size,
                              hipStream_t stream) {
    const float* pred = (const float*)d_in[0];
    const float* targ = (const float*)d_in[1];
    float* out = (float*)d_out;
    float* ws  = (float*)d_ws;

    WB wb;
    {
        double gg[11], sum = 0.0;
        for (int k = 0; k < 11; ++k) {
            const double d = (double)(k - 5);
            gg[k] = exp(-d * d / 4.5);
            sum += gg[k];
        }
        double sbf = 0.0;
        for (int k = 0; k < 11; ++k) {
            union { float f; unsigned int u; } cv;
            cv.f = (float)(gg[k] / sum);
            const unsigned int r = (cv.u + 0x7fffu + ((cv.u >> 16) & 1u)) >> 16;
            wb.b[k] = (unsigned short)r;
            union { float f; unsigned int u; } bk;
            bk.u = r << 16;
            sbf += (double)bk.f;
        }
        const double s2 = sbf * sbf;       // acc = s2 * true value
        wb.c2 = (float)s2;
        wb.k1 = (float)(0.0001 * s2 * s2); // C1 in acc^2 units
        wb.k2 = (float)(0.0009 * s2 * s2); // C2 in acc^2 units
    }

    hipMemsetAsync(ws, 0, NACC * sizeof(float), stream);
    ssim_tiled<<<NBLOCKS, BLOCK, 0, stream>>>(pred, targ, ws, wb);
    ssim_finalize<<<1, 64, 0, stream>>>(ws, out);
}